// Round 1
// baseline (533.054 us; speedup 1.0000x reference)
//
#include <hip/hip_runtime.h>
#include <hip/hip_bf16.h>
#include <cstdint>

#define MODEL_DIM 1024
#define NUM_HEADS 16
#define HEAD_DIM 64
#define BATCH 4
#define SEQ 2048
#define M_TOT (BATCH * SEQ) /* 8192 */

typedef float f32x4 __attribute__((ext_vector_type(4)));
typedef unsigned short ushort8 __attribute__((ext_vector_type(8)));
typedef __bf16 bf16x8 __attribute__((ext_vector_type(8)));

union BF8 { ushort8 u; bf16x8 b; };

__device__ inline unsigned short f2bf(float f) {
  union { float f; unsigned int u; } x;
  x.f = f;
  unsigned int u = x.u;
  u += 0x7fffu + ((u >> 16) & 1u); // RNE
  return (unsigned short)(u >> 16);
}

__device__ inline f32x4 mfma16(bf16x8 a, bf16x8 b, f32x4 c) {
  return __builtin_amdgcn_mfma_f32_16x16x32_bf16(a, b, c, 0, 0, 0);
}

// C[m][n] = sum_k A[m][k] * W[n][k] + bias[n]
// A: [M][1024] (fp32 or bf16-bits), W: [1024][1024] fp32 (row n = output col, i.e. B^T form)
// 128x128 tile, 256 threads = 4 waves (2x2), BK=32, padded LDS (stride 40 ushorts).
template <bool A_BF16, bool OUT_BF16>
__global__ __launch_bounds__(256) void gemm_bias_kernel(
    const void* __restrict__ Ap, const float* __restrict__ W,
    const float* __restrict__ bias, void* __restrict__ Cp) {
  const int K = MODEL_DIM, N = MODEL_DIM;
  const int ntiles = N / 128; // 8
  const int m0 = (int)(blockIdx.x / ntiles) * 128;
  const int n0 = (int)(blockIdx.x % ntiles) * 128;

  __shared__ unsigned short As[128 * 40];
  __shared__ unsigned short Bs[128 * 40];

  const int tid = threadIdx.x;
  const int lane = tid & 63, wid = tid >> 6;
  const int l15 = lane & 15, lg = lane >> 4;
  const int wm = wid >> 1, wn = wid & 1;
  const int sr = tid >> 1, sc = (tid & 1) * 16;

  f32x4 zero = {0.f, 0.f, 0.f, 0.f};
  f32x4 acc[4][4];
#pragma unroll
  for (int i = 0; i < 4; ++i)
#pragma unroll
    for (int j = 0; j < 4; ++j) acc[i][j] = zero;

  for (int k0 = 0; k0 < K; k0 += 32) {
    // ---- stage A tile (rows m0..m0+127, cols k0..k0+31) ----
    if (A_BF16) {
      const unsigned short* src =
          (const unsigned short*)Ap + (size_t)(m0 + sr) * K + k0 + sc;
      ushort8 v0 = *(const ushort8*)(src);
      ushort8 v1 = *(const ushort8*)(src + 8);
      *(ushort8*)(&As[sr * 40 + sc]) = v0;
      *(ushort8*)(&As[sr * 40 + sc + 8]) = v1;
    } else {
      const float* src = (const float*)Ap + (size_t)(m0 + sr) * K + k0 + sc;
      float fv[16];
#pragma unroll
      for (int q = 0; q < 4; ++q) {
        float4 t = reinterpret_cast<const float4*>(src)[q];
        fv[q * 4 + 0] = t.x;
        fv[q * 4 + 1] = t.y;
        fv[q * 4 + 2] = t.z;
        fv[q * 4 + 3] = t.w;
      }
      ushort8 u0, u1;
#pragma unroll
      for (int j = 0; j < 8; ++j) {
        u0[j] = f2bf(fv[j]);
        u1[j] = f2bf(fv[8 + j]);
      }
      *(ushort8*)(&As[sr * 40 + sc]) = u0;
      *(ushort8*)(&As[sr * 40 + sc + 8]) = u1;
    }
    // ---- stage B tile (W rows n0..n0+127, cols k0..k0+31) ----
    {
      const float* src = W + (size_t)(n0 + sr) * K + k0 + sc;
      float fv[16];
#pragma unroll
      for (int q = 0; q < 4; ++q) {
        float4 t = reinterpret_cast<const float4*>(src)[q];
        fv[q * 4 + 0] = t.x;
        fv[q * 4 + 1] = t.y;
        fv[q * 4 + 2] = t.z;
        fv[q * 4 + 3] = t.w;
      }
      ushort8 u0, u1;
#pragma unroll
      for (int j = 0; j < 8; ++j) {
        u0[j] = f2bf(fv[j]);
        u1[j] = f2bf(fv[8 + j]);
      }
      *(ushort8*)(&Bs[sr * 40 + sc]) = u0;
      *(ushort8*)(&Bs[sr * 40 + sc + 8]) = u1;
    }
    __syncthreads();

    BF8 af[4], bfr[4];
#pragma unroll
    for (int t = 0; t < 4; ++t) {
      af[t].u = *(const ushort8*)(&As[(wm * 64 + t * 16 + l15) * 40 + lg * 8]);
      bfr[t].u = *(const ushort8*)(&Bs[(wn * 64 + t * 16 + l15) * 40 + lg * 8]);
    }
#pragma unroll
    for (int mt = 0; mt < 4; ++mt)
#pragma unroll
      for (int nt = 0; nt < 4; ++nt)
        acc[mt][nt] = mfma16(af[mt].b, bfr[nt].b, acc[mt][nt]);
    __syncthreads();
  }

  // ---- epilogue: bias + store ----
#pragma unroll
  for (int nt = 0; nt < 4; ++nt) {
    const int col = n0 + wn * 64 + nt * 16 + l15;
    const float bv = bias[col];
#pragma unroll
    for (int mt = 0; mt < 4; ++mt) {
#pragma unroll
      for (int i = 0; i < 4; ++i) {
        const int row = m0 + wm * 64 + mt * 16 + lg * 4 + i;
        const float v = acc[mt][nt][i] + bv;
        if (OUT_BF16)
          ((unsigned short*)Cp)[(size_t)row * N + col] = f2bf(v);
        else
          ((float*)Cp)[(size_t)row * N + col] = v;
      }
    }
  }
}

// Causal flash attention. Q/K/V: bf16 bits, layout [B][S][H*64] (GEMM output layout).
// Grid: B*H*(S/64) blocks, 256 threads = 4 independent waves, 16 q-rows per wave.
__global__ __launch_bounds__(256) void attn_kernel(
    const unsigned short* __restrict__ Qb, const unsigned short* __restrict__ Kb,
    const unsigned short* __restrict__ Vb, unsigned short* __restrict__ Ctx) {
  const int bx = blockIdx.x;
  const int qt = bx & 31;
  const int h = (bx >> 5) & 15;
  const int b = bx >> 9;
  const int tid = threadIdx.x;
  const int lane = tid & 63, wid = tid >> 6;
  const int l15 = lane & 15, lg = lane >> 4;
  const int q0 = qt * 64;
  const int r0 = q0 + wid * 16;
  const size_t base = ((size_t)b * SEQ) * MODEL_DIM + h * HEAD_DIM;

  __shared__ unsigned short pbuf[4][16 * 40]; // per-wave P transpose buffer
  unsigned short* pb = pbuf[wid];

  f32x4 zero = {0.f, 0.f, 0.f, 0.f};

  // Q fragments: row r0+l15, k = kk*32 + lg*8 + j
  BF8 qf[2];
  {
    const unsigned short* qp = Qb + base + (size_t)(r0 + l15) * MODEL_DIM + lg * 8;
    qf[0].u = *(const ushort8*)qp;
    qf[1].u = *(const ushort8*)(qp + 32);
  }

  float mi[4], li[4];
  f32x4 o[4];
#pragma unroll
  for (int i = 0; i < 4; ++i) {
    mi[i] = -1e30f;
    li[i] = 0.f;
  }
#pragma unroll
  for (int d = 0; d < 4; ++d) o[d] = zero;

  const int kend = r0 + 16; // causal: max k index is r0+15
  for (int k0 = 0; k0 < kend; k0 += 32) {
    // ---- S = Q K^T for 16q x 32k ----
    f32x4 st[2];
#pragma unroll
    for (int hh = 0; hh < 2; ++hh) {
      const unsigned short* kp =
          Kb + base + (size_t)(k0 + hh * 16 + l15) * MODEL_DIM + lg * 8;
      BF8 ka, kc;
      ka.u = *(const ushort8*)kp;
      kc.u = *(const ushort8*)(kp + 32);
      f32x4 a = zero;
      a = mfma16(qf[0].b, ka.b, a);
      a = mfma16(qf[1].b, kc.b, a);
      st[hh] = a;
    }
    // ---- scale + causal mask ----
    float sv[2][4];
#pragma unroll
    for (int hh = 0; hh < 2; ++hh)
#pragma unroll
      for (int i = 0; i < 4; ++i) {
        const int col = k0 + hh * 16 + l15;
        const int row = r0 + lg * 4 + i;
        const float v = st[hh][i] * 0.125f; // 1/sqrt(64)
        sv[hh][i] = (col <= row) ? v : -1e30f;
      }
    // ---- online softmax (rows live on 16-lane groups) ----
#pragma unroll
    for (int i = 0; i < 4; ++i) {
      float mx = fmaxf(sv[0][i], sv[1][i]);
      mx = fmaxf(mx, __shfl_xor(mx, 1));
      mx = fmaxf(mx, __shfl_xor(mx, 2));
      mx = fmaxf(mx, __shfl_xor(mx, 4));
      mx = fmaxf(mx, __shfl_xor(mx, 8));
      const float mn = fmaxf(mi[i], mx);
      const float scale = __expf(mi[i] - mn);
      const float p0 = __expf(sv[0][i] - mn);
      const float p1 = __expf(sv[1][i] - mn);
      float rs = p0 + p1;
      rs += __shfl_xor(rs, 1);
      rs += __shfl_xor(rs, 2);
      rs += __shfl_xor(rs, 4);
      rs += __shfl_xor(rs, 8);
      li[i] = li[i] * scale + rs;
      mi[i] = mn;
#pragma unroll
      for (int d = 0; d < 4; ++d) o[d][i] *= scale;
      // write P (bf16) for transpose: row = q-in-tile, col = k-in-tile
      pb[(lg * 4 + i) * 40 + l15] = f2bf(p0);
      pb[(lg * 4 + i) * 40 + 16 + l15] = f2bf(p1);
    }
    // ---- read P as A-fragment (wave-internal LDS RAW; compiler inserts lgkmcnt) ----
    BF8 pf;
    pf.u = *(const ushort8*)(&pb[l15 * 40 + lg * 8]);
    // ---- O += P V ----
#pragma unroll
    for (int d = 0; d < 4; ++d) {
      BF8 vf;
#pragma unroll
      for (int j = 0; j < 8; ++j) {
        vf.u[j] = Vb[base + (size_t)(k0 + lg * 8 + j) * MODEL_DIM + d * 16 + l15];
      }
      o[d] = mfma16(pf.b, vf.b, o[d]);
    }
  }

  // ---- normalize + store ctx ----
#pragma unroll
  for (int d = 0; d < 4; ++d)
#pragma unroll
    for (int i = 0; i < 4; ++i) {
      const float v = o[d][i] / li[i];
      Ctx[base + (size_t)(r0 + lg * 4 + i) * MODEL_DIM + d * 16 + l15] = f2bf(v);
    }
}

extern "C" void kernel_launch(void* const* d_in, const int* in_sizes, int n_in,
                              void* d_out, int out_size, void* d_ws, size_t ws_size,
                              hipStream_t stream) {
  (void)in_sizes; (void)n_in; (void)out_size; (void)ws_size;
  const float* query = (const float*)d_in[0];
  const float* key = (const float*)d_in[1];
  const float* value = (const float*)d_in[2];
  // d_in[3] = mask (tril causal) — implemented analytically in attn_kernel
  const float* wq = (const float*)d_in[4];
  const float* bq = (const float*)d_in[5];
  const float* wk = (const float*)d_in[6];
  const float* bk = (const float*)d_in[7];
  const float* wv = (const float*)d_in[8];
  const float* bv = (const float*)d_in[9];
  const float* wo = (const float*)d_in[10];
  const float* bo = (const float*)d_in[11];

  unsigned short* Qb = (unsigned short*)d_ws;
  unsigned short* Kb = Qb + (size_t)M_TOT * MODEL_DIM;
  unsigned short* Vb = Kb + (size_t)M_TOT * MODEL_DIM;
  // Ctx aliases Qb: each attn block reads its Q region into registers before
  // writing ctx to the same (block-unique) region. Saves 16MB of ws.
  unsigned short* Ctx = Qb;

  const dim3 gg(512), gb(256);
  gemm_bias_kernel<false, true><<<gg, gb, 0, stream>>>(query, wq, bq, Qb);
  gemm_bias_kernel<false, true><<<gg, gb, 0, stream>>>(key, wk, bk, Kb);
  gemm_bias_kernel<false, true><<<gg, gb, 0, stream>>>(value, wv, bv, Vb);

  attn_kernel<<<dim3(BATCH * NUM_HEADS * (SEQ / 64)), gb, 0, stream>>>(Qb, Kb, Vb, Ctx);

  gemm_bias_kernel<true, false><<<gg, gb, 0, stream>>>(Ctx, wo, bo, (float*)d_out);
}